// Round 13
// baseline (151.322 us; speedup 1.0000x reference)
//
#include <hip/hip_runtime.h>
#include <hip/hip_bf16.h>
#include <stdint.h>

#define B_ 4
#define C_ 256
#define N_ 4096
#define D_ 32
#define KT 256   // keys per outer iteration

typedef __bf16 bf16_t;
typedef __bf16 bf16x4_t __attribute__((ext_vector_type(4)));
typedef __bf16 bf16x8_t __attribute__((ext_vector_type(8)));
typedef float  f32x4    __attribute__((ext_vector_type(4)));

// ---------------------------------------------------------------------------
// cast W (wq|wk|wv) -> Wb bf16 [320][256]
// ---------------------------------------------------------------------------
__global__ __launch_bounds__(256) void cast_w_kernel(
    const float* __restrict__ wq, const float* __restrict__ wk,
    const float* __restrict__ wv, bf16_t* __restrict__ Wb)
{
  const int gr = blockIdx.x;
  const int t  = threadIdx.x;
  float v;
  if (gr < 32)      v = wq[gr * C_ + t];
  else if (gr < 64) v = wk[(gr - 32) * C_ + t];
  else              v = wv[(gr - 64) * C_ + t];
  Wb[gr * C_ + t] = (bf16_t)v;
}

// ---------------------------------------------------------------------------
// Projection GEMM with FUSED transpose (R12, unchanged): reads x f32 direct,
// stages 64x64 f32 tile in LDS, cvt at fragment build. Q pre-scaled log2(e).
// ---------------------------------------------------------------------------
__global__ __launch_bounds__(256) void proj_kernel(
    const float* __restrict__ x, const bf16_t* __restrict__ Wb,
    const float* __restrict__ bq, const float* __restrict__ bk,
    const float* __restrict__ bv,
    bf16_t* __restrict__ Qh, bf16_t* __restrict__ Kh, bf16_t* __restrict__ Vh)
{
  __shared__ float xs[64][65];
  const int bi = blockIdx.x;
  const int b  = bi & 3;
  const int n0 = (bi >> 2) * 64;
  const int t = threadIdx.x, w = t >> 6, lane = t & 63;
  const int l4 = lane >> 4, lm = lane & 15;

  const f32x4 z4 = {0.f, 0.f, 0.f, 0.f};
  f32x4 acc[5][4];
#pragma unroll
  for (int rt = 0; rt < 5; ++rt)
#pragma unroll
    for (int ct = 0; ct < 4; ++ct) acc[rt][ct] = z4;

  const int lr = t >> 2;
  const int lc = (t & 3) * 16;

#pragma unroll 1
  for (int k0 = 0; k0 < C_; k0 += 64) {
    __syncthreads();
#pragma unroll
    for (int i = 0; i < 4; ++i) {
      const f32x4 v = *(const f32x4*)(x + ((size_t)(b * C_ + k0 + lr)) * N_ + n0 + lc + i * 4);
      xs[lr][lc + i * 4 + 0] = v[0];
      xs[lr][lc + i * 4 + 1] = v[1];
      xs[lr][lc + i * 4 + 2] = v[2];
      xs[lr][lc + i * 4 + 3] = v[3];
    }
    __syncthreads();

    bf16x8_t af[5][2], bfr[4][2];
#pragma unroll
    for (int rt = 0; rt < 5; ++rt)
#pragma unroll
      for (int kc = 0; kc < 2; ++kc)
        af[rt][kc] = *(const bf16x8_t*)(Wb + (size_t)(w * 80 + rt * 16 + lm) * C_ + k0 + kc * 32 + l4 * 8);
#pragma unroll
    for (int ct = 0; ct < 4; ++ct)
#pragma unroll
      for (int kc = 0; kc < 2; ++kc) {
        bf16_t tmp[8];
#pragma unroll
        for (int j = 0; j < 8; ++j)
          tmp[j] = (bf16_t)xs[kc * 32 + l4 * 8 + j][ct * 16 + lm];
        bfr[ct][kc] = *(bf16x8_t*)tmp;
      }
#pragma unroll
    for (int rt = 0; rt < 5; ++rt)
#pragma unroll
      for (int ct = 0; ct < 4; ++ct)
#pragma unroll
        for (int kc = 0; kc < 2; ++kc)
          acc[rt][ct] = __builtin_amdgcn_mfma_f32_16x16x32_bf16(af[rt][kc], bfr[ct][kc], acc[rt][ct], 0, 0, 0);
  }

#pragma unroll
  for (int rt = 0; rt < 5; ++rt)
#pragma unroll
    for (int r = 0; r < 4; ++r) {
      const int gr = w * 80 + rt * 16 + 4 * l4 + r;
      const float bias = (gr < 32) ? bq[gr] : (gr < 64) ? bk[gr - 32] : bv[gr - 64];
#pragma unroll
      for (int ct = 0; ct < 4; ++ct) {
        const int n = n0 + ct * 16 + lm;
        float v = acc[rt][ct][r] + bias;
        if (gr < 32) {
          v *= 1.44269504088896f;
          Qh[((size_t)(b * N_ + n)) * D_ + gr] = (bf16_t)v;
        } else if (gr < 64) {
          Kh[((size_t)(b * N_ + n)) * D_ + (gr - 32)] = (bf16_t)v;
        } else {
          Vh[((size_t)(b * C_ + (gr - 64))) * N_ + n] = (bf16_t)v;
        }
      }
    }
}

// ---------------------------------------------------------------------------
// Flash attention, fixed-reference exp2 softmax, REPARTITIONED waves:
// 8 waves = (qh 0..1 q-halves of 32) x (cg 0..3 ch-groups of 64).
// Wave (qh,cg): S/exp2/P-write for q[qh*32,+32) x keys[cg*64,+64) (zero
// redundancy); PV for ch[cg*64,+64) x its 32 q over all 256 keys.
// P-read traffic HALVED vs R8 (wave reads only its 32-q half: 16KB/iter);
// each pa fragment feeds 4 MFMAs (was 2). All other per-CU totals identical.
// P double-buffered, ONE lgkm-only barrier/iter, l lane-local + epilogue.
// ---------------------------------------------------------------------------
__global__ __launch_bounds__(512, 2) void attn_kernel(
    const bf16_t* __restrict__ Qh, const bf16_t* __restrict__ Kh,
    const bf16_t* __restrict__ Vh, const float* __restrict__ x,
    const float* __restrict__ gamma, float* __restrict__ out)
{
  __shared__ __align__(16) bf16_t Pl[2][64][KT];  // 64 KB double-buffered P
  __shared__ __align__(16) float  Lx[64][12];     // epilogue l exchange (4 cg cols)

  const int bi = blockIdx.x;
  const int xcd = bi & 7, slot = bi >> 3;
  const int b  = xcd >> 1;                 // 2 XCDs per batch -> K,V,Q L2-resident
  const int q0 = ((xcd & 1) * 32 + slot) * 64;

  const int t = threadIdx.x, w = t >> 6, lane = t & 63;
  const int l4 = lane >> 4, lm = lane & 15;
  const int qh = w >> 2, cg = w & 3;
  const int swz = (lm & 7) << 3;

  const f32x4 z4 = {0.f, 0.f, 0.f, 0.f};

  // Q fragments: 2 q-subtiles of 16 within this wave's q-half
  bf16x8_t qf[2];
#pragma unroll
  for (int rt = 0; rt < 2; ++rt)
    qf[rt] = *(const bf16x8_t*)(Qh + ((size_t)(b * N_ + q0 + qh * 32 + rt * 16 + lm)) * D_ + l4 * 8);

  // K: wave's 64-key slice of each 256-key tile; V: wave's 64 channels
  const bf16_t* kbase = Kh + ((size_t)(b * N_ + cg * 64 + lm)) * D_ + l4 * 8;
  const bf16_t* vbase = Vh + ((size_t)(b * C_ + cg * 64 + lm)) * N_ + l4 * 8;

  f32x4 acc[4][2];   // [ct][rt] : 64 ch x 32 q
#pragma unroll
  for (int ct = 0; ct < 4; ++ct)
#pragma unroll
    for (int rt = 0; rt < 2; ++rt) acc[ct][rt] = z4;
  float l_run[2] = {0.f, 0.f};   // lane-local partial denominators

  // prologue: K tile 0; V fragments for substeps 0 and 1
  bf16x8_t kf[4], kn[4];
#pragma unroll
  for (int mt = 0; mt < 4; ++mt)
    kf[mt] = *(const bf16x8_t*)(kbase + (size_t)(mt * 16) * D_);
  bf16x8_t vf0[4][2], vf1[4][2];
#pragma unroll
  for (int ct = 0; ct < 4; ++ct)
#pragma unroll
    for (int kc = 0; kc < 2; ++kc) {
      vf0[ct][kc] = *(const bf16x8_t*)(vbase + (size_t)(ct * 16) * N_ + kc * 32);
      vf1[ct][kc] = *(const bf16x8_t*)(vbase + (size_t)(ct * 16) * N_ + 64 + kc * 32);
    }

#pragma unroll 1
  for (int it = 0; it < N_ / KT; ++it) {
    const int buf = it & 1;

    // ---- S: this wave's 32 q x its 64 keys ----
    f32x4 S[2][4];
#pragma unroll
    for (int rt = 0; rt < 2; ++rt)
#pragma unroll
      for (int mt = 0; mt < 4; ++mt)
        S[rt][mt] = __builtin_amdgcn_mfma_f32_16x16x32_bf16(kf[mt], qf[rt], z4, 0, 0, 0);

    // prefetch next iter's K slice (in flight across exp2+PV)
    const int k0n = ((it + 1) * KT) & (N_ - 1);
#pragma unroll
    for (int mt = 0; mt < 4; ++mt)
      kn[mt] = *(const bf16x8_t*)(kbase + (size_t)(k0n + mt * 16) * D_);

    // ---- p = exp2(S) (fixed reference 0), P write, local l acc ----
#pragma unroll
    for (int rt = 0; rt < 2; ++rt) {
      const int prow = qh * 32 + rt * 16 + lm;
#pragma unroll
      for (int mt = 0; mt < 4; ++mt) {
        const float p0 = __builtin_amdgcn_exp2f(S[rt][mt][0]);
        const float p1 = __builtin_amdgcn_exp2f(S[rt][mt][1]);
        const float p2 = __builtin_amdgcn_exp2f(S[rt][mt][2]);
        const float p3 = __builtin_amdgcn_exp2f(S[rt][mt][3]);
        l_run[rt] += (p0 + p1) + (p2 + p3);
        bf16x4_t w4 = {(bf16_t)p0, (bf16_t)p1, (bf16_t)p2, (bf16_t)p3};
        *(bf16x4_t*)&Pl[buf][prow][(cg * 64 + mt * 16 + 4 * l4) ^ swz] = w4;
      }
    }

    asm volatile("s_waitcnt lgkmcnt(0)" ::: "memory");   // P visible; prev reads drained
    __builtin_amdgcn_s_barrier();

    // ---- PV: 4 barrier-free substeps x 64 keys; 64 ch per wave ----
#pragma unroll
    for (int s4 = 0; s4 < 4; ++s4) {
      bf16x8_t pa[2][2];
#pragma unroll
      for (int rt = 0; rt < 2; ++rt)
#pragma unroll
        for (int kc = 0; kc < 2; ++kc)
          pa[rt][kc] = *(const bf16x8_t*)&Pl[buf][qh * 32 + rt * 16 + lm][(s4 * 64 + kc * 32 + l4 * 8) ^ swz];
      const int knx = (it * KT + (s4 + 2) * 64) & (N_ - 1);
      if ((s4 & 1) == 0) {
#pragma unroll
        for (int ct = 0; ct < 4; ++ct)
#pragma unroll
          for (int kc = 0; kc < 2; ++kc)
#pragma unroll
            for (int rt = 0; rt < 2; ++rt)
              acc[ct][rt] = __builtin_amdgcn_mfma_f32_16x16x32_bf16(vf0[ct][kc], pa[rt][kc], acc[ct][rt], 0, 0, 0);
#pragma unroll
        for (int ct = 0; ct < 4; ++ct)
#pragma unroll
          for (int kc = 0; kc < 2; ++kc)
            vf0[ct][kc] = *(const bf16x8_t*)(vbase + (size_t)(ct * 16) * N_ + knx + kc * 32);
      } else {
#pragma unroll
        for (int ct = 0; ct < 4; ++ct)
#pragma unroll
          for (int kc = 0; kc < 2; ++kc)
#pragma unroll
            for (int rt = 0; rt < 2; ++rt)
              acc[ct][rt] = __builtin_amdgcn_mfma_f32_16x16x32_bf16(vf1[ct][kc], pa[rt][kc], acc[ct][rt], 0, 0, 0);
#pragma unroll
        for (int ct = 0; ct < 4; ++ct)
#pragma unroll
          for (int kc = 0; kc < 2; ++kc)
            vf1[ct][kc] = *(const bf16x8_t*)(vbase + (size_t)(ct * 16) * N_ + knx + kc * 32);
      }
    }

#pragma unroll
    for (int mt = 0; mt < 4; ++mt) kf[mt] = kn[mt];
  }

  // ---- epilogue: l reduce (lane -> wave -> cross-cg), then store ----
#pragma unroll
  for (int rt = 0; rt < 2; ++rt) {
    l_run[rt] += __shfl_xor(l_run[rt], 16);
    l_run[rt] += __shfl_xor(l_run[rt], 32);
  }
  if (l4 == 0) {
#pragma unroll
    for (int rt = 0; rt < 2; ++rt) Lx[qh * 32 + rt * 16 + lm][cg] = l_run[rt];
  }
  asm volatile("s_waitcnt lgkmcnt(0)" ::: "memory");
  __builtin_amdgcn_s_barrier();

  const float g = gamma[0];
#pragma unroll
  for (int rt = 0; rt < 2; ++rt) {
    const f32x4 s0 = *(const f32x4*)&Lx[qh * 32 + rt * 16 + lm][0];
    const float lt = (s0[0] + s0[1]) + (s0[2] + s0[3]);
    const float inv = 1.f / lt;
    const int n = q0 + qh * 32 + rt * 16 + lm;
#pragma unroll
    for (int ct = 0; ct < 4; ++ct) {
#pragma unroll
      for (int r = 0; r < 4; ++r) {
        const int c = cg * 64 + ct * 16 + 4 * l4 + r;
        const size_t idx = ((size_t)(b * C_ + c)) * N_ + n;
        out[idx] = g * (acc[ct][rt][r] * inv) + x[idx];
      }
    }
  }
}

extern "C" void kernel_launch(void* const* d_in, const int* in_sizes, int n_in,
                              void* d_out, int out_size, void* d_ws, size_t ws_size,
                              hipStream_t stream) {
  const float* x     = (const float*)d_in[0];
  const float* wq    = (const float*)d_in[1];
  const float* bq    = (const float*)d_in[2];
  const float* wk    = (const float*)d_in[3];
  const float* bk    = (const float*)d_in[4];
  const float* wv    = (const float*)d_in[5];
  const float* bv    = (const float*)d_in[6];
  const float* gamma = (const float*)d_in[7];
  float* out = (float*)d_out;

  bf16_t* Qh = (bf16_t*)d_ws;
  bf16_t* Kh = Qh + (size_t)B_ * N_ * D_;
  bf16_t* Vh = Kh + (size_t)B_ * N_ * D_;
  bf16_t* Wb = Vh + (size_t)B_ * C_ * N_;

  cast_w_kernel<<<320, 256, 0, stream>>>(wq, wk, wv, Wb);
  proj_kernel<<<256, 256, 0, stream>>>(x, Wb, bq, bk, bv, Qh, Kh, Vh);
  attn_kernel<<<256, 512, 0, stream>>>(Qh, Kh, Vh, x, gamma, out);
}

// Round 14
// 96.360 us; speedup vs baseline: 1.5704x; 1.5704x over previous
//
#include <hip/hip_runtime.h>
#include <hip/hip_bf16.h>
#include <stdint.h>

#define B_ 4
#define C_ 256
#define N_ 4096
#define D_ 32
#define KT 256   // keys per outer iteration

typedef __bf16 bf16_t;
typedef __bf16 bf16x4_t __attribute__((ext_vector_type(4)));
typedef __bf16 bf16x8_t __attribute__((ext_vector_type(8)));
typedef float  f32x4    __attribute__((ext_vector_type(4)));

// ---------------------------------------------------------------------------
// cast W (wq|wk|wv) -> Wb bf16 [320][256]
// ---------------------------------------------------------------------------
__global__ __launch_bounds__(256) void cast_w_kernel(
    const float* __restrict__ wq, const float* __restrict__ wk,
    const float* __restrict__ wv, bf16_t* __restrict__ Wb)
{
  const int gr = blockIdx.x;
  const int t  = threadIdx.x;
  float v;
  if (gr < 32)      v = wq[gr * C_ + t];
  else if (gr < 64) v = wk[(gr - 32) * C_ + t];
  else              v = wv[(gr - 64) * C_ + t];
  Wb[gr * C_ + t] = (bf16_t)v;
}

// ---------------------------------------------------------------------------
// Projection GEMM with fused transpose (R12, unchanged).
// ---------------------------------------------------------------------------
__global__ __launch_bounds__(256) void proj_kernel(
    const float* __restrict__ x, const bf16_t* __restrict__ Wb,
    const float* __restrict__ bq, const float* __restrict__ bk,
    const float* __restrict__ bv,
    bf16_t* __restrict__ Qh, bf16_t* __restrict__ Kh, bf16_t* __restrict__ Vh)
{
  __shared__ float xs[64][65];
  const int bi = blockIdx.x;
  const int b  = bi & 3;
  const int n0 = (bi >> 2) * 64;
  const int t = threadIdx.x, w = t >> 6, lane = t & 63;
  const int l4 = lane >> 4, lm = lane & 15;

  const f32x4 z4 = {0.f, 0.f, 0.f, 0.f};
  f32x4 acc[5][4];
#pragma unroll
  for (int rt = 0; rt < 5; ++rt)
#pragma unroll
    for (int ct = 0; ct < 4; ++ct) acc[rt][ct] = z4;

  const int lr = t >> 2;
  const int lc = (t & 3) * 16;

#pragma unroll 1
  for (int k0 = 0; k0 < C_; k0 += 64) {
    __syncthreads();
#pragma unroll
    for (int i = 0; i < 4; ++i) {
      const f32x4 v = *(const f32x4*)(x + ((size_t)(b * C_ + k0 + lr)) * N_ + n0 + lc + i * 4);
      xs[lr][lc + i * 4 + 0] = v[0];
      xs[lr][lc + i * 4 + 1] = v[1];
      xs[lr][lc + i * 4 + 2] = v[2];
      xs[lr][lc + i * 4 + 3] = v[3];
    }
    __syncthreads();

    bf16x8_t af[5][2], bfr[4][2];
#pragma unroll
    for (int rt = 0; rt < 5; ++rt)
#pragma unroll
      for (int kc = 0; kc < 2; ++kc)
        af[rt][kc] = *(const bf16x8_t*)(Wb + (size_t)(w * 80 + rt * 16 + lm) * C_ + k0 + kc * 32 + l4 * 8);
#pragma unroll
    for (int ct = 0; ct < 4; ++ct)
#pragma unroll
      for (int kc = 0; kc < 2; ++kc) {
        bf16_t tmp[8];
#pragma unroll
        for (int j = 0; j < 8; ++j)
          tmp[j] = (bf16_t)xs[kc * 32 + l4 * 8 + j][ct * 16 + lm];
        bfr[ct][kc] = *(bf16x8_t*)tmp;
      }
#pragma unroll
    for (int rt = 0; rt < 5; ++rt)
#pragma unroll
      for (int ct = 0; ct < 4; ++ct)
#pragma unroll
        for (int kc = 0; kc < 2; ++kc)
          acc[rt][ct] = __builtin_amdgcn_mfma_f32_16x16x32_bf16(af[rt][kc], bfr[ct][kc], acc[rt][ct], 0, 0, 0);
  }

#pragma unroll
  for (int rt = 0; rt < 5; ++rt)
#pragma unroll
    for (int r = 0; r < 4; ++r) {
      const int gr = w * 80 + rt * 16 + 4 * l4 + r;
      const float bias = (gr < 32) ? bq[gr] : (gr < 64) ? bk[gr - 32] : bv[gr - 64];
#pragma unroll
      for (int ct = 0; ct < 4; ++ct) {
        const int n = n0 + ct * 16 + lm;
        float v = acc[rt][ct][r] + bias;
        if (gr < 32) {
          v *= 1.44269504088896f;
          Qh[((size_t)(b * N_ + n)) * D_ + gr] = (bf16_t)v;
        } else if (gr < 64) {
          Kh[((size_t)(b * N_ + n)) * D_ + (gr - 32)] = (bf16_t)v;
        } else {
          Vh[((size_t)(b * C_ + (gr - 64))) * N_ + n] = (bf16_t)v;
        }
      }
    }
}

// ---------------------------------------------------------------------------
// Flash attention, 1024-thread block (16 waves = 4/SIMD): TLP doubled at
// EXACTLY constant per-CU traffic (same P buffer, V/K coverage split finer).
// S/exp2/P-write: wave w owns keys [w*16,+16) of each 256-tile (16-way split,
// zero redundancy). PV: wave (cg=w>>1, kh=w&1) covers ch[cg*32,+32) x its
// 128-key half -> each (ch,key) V elem read once per block; P-reads
// 16KB/wave/iter (block total = R8's 256KB). acc pairs (cg,0/1) combined at
// epilogue through retired Pl space. ONE lgkm barrier per iter, l lane-local.
// ---------------------------------------------------------------------------
__global__ __launch_bounds__(1024) void attn_kernel(
    const bf16_t* __restrict__ Qh, const bf16_t* __restrict__ Kh,
    const bf16_t* __restrict__ Vh, const float* __restrict__ x,
    const float* __restrict__ gamma, float* __restrict__ out)
{
  __shared__ __align__(16) bf16_t Pl[2][64][KT];  // 64 KB double-buffered P
  __shared__ __align__(16) float  Lx[64][20];     // epilogue l exchange (16 wave cols)

  const int bi = blockIdx.x;
  const int xcd = bi & 7, slot = bi >> 3;
  const int b  = xcd >> 1;                 // 2 XCDs per batch -> K,V,Q L2-resident
  const int q0 = ((xcd & 1) * 32 + slot) * 64;

  const int t = threadIdx.x, w = t >> 6, lane = t & 63;
  const int l4 = lane >> 4, lm = lane & 15;
  const int cg = w >> 1, kh = w & 1;
  const int swz = (lm & 7) << 3;

  const f32x4 z4 = {0.f, 0.f, 0.f, 0.f};

  // Q fragments: 4 q-subtiles of 16 (whole 64-q tile, held in regs)
  bf16x8_t qf[4];
#pragma unroll
  for (int rt = 0; rt < 4; ++rt)
    qf[rt] = *(const bf16x8_t*)(Qh + ((size_t)(b * N_ + q0 + rt * 16 + lm)) * D_ + l4 * 8);

  // K: wave's 16-key slice of each 256-key tile
  const bf16_t* kbase = Kh + ((size_t)(b * N_ + w * 16 + lm)) * D_ + l4 * 8;
  // V: wave's 32 channels, its 128-key half
  const bf16_t* vbase = Vh + ((size_t)(b * C_ + cg * 32 + lm)) * N_ + kh * 128 + l4 * 8;

  f32x4 acc[2][4];   // [ct][rt] : 32 ch x 64 q (partial over kh's keys)
#pragma unroll
  for (int ct = 0; ct < 2; ++ct)
#pragma unroll
    for (int rt = 0; rt < 4; ++rt) acc[ct][rt] = z4;
  float l_run[4] = {0.f, 0.f, 0.f, 0.f};

  // prologue: K slice 0; V fragments for substeps 0/1 of the wave's half
  bf16x8_t kf;
  kf = *(const bf16x8_t*)(kbase);
  bf16x8_t vf0[2], vf1[2];
#pragma unroll
  for (int ct = 0; ct < 2; ++ct) {
    vf0[ct] = *(const bf16x8_t*)(vbase + (size_t)(ct * 16) * N_);
    vf1[ct] = *(const bf16x8_t*)(vbase + (size_t)(ct * 16) * N_ + 32);
  }

#pragma unroll 1
  for (int it = 0; it < N_ / KT; ++it) {
    const int buf = it & 1;

    // ---- S: 64 q x this wave's 16 keys (1 fragment) ----
    f32x4 S[4];
#pragma unroll
    for (int rt = 0; rt < 4; ++rt)
      S[rt] = __builtin_amdgcn_mfma_f32_16x16x32_bf16(kf, qf[rt], z4, 0, 0, 0);

    // prefetch next iter's K slice
    const int k0n = ((it + 1) * KT) & (N_ - 1);
    bf16x8_t kn = *(const bf16x8_t*)(kbase + (size_t)k0n * D_);

    // ---- p = exp2(S) (fixed ref 0), P write (16 keys x 64 q), local l ----
#pragma unroll
    for (int rt = 0; rt < 4; ++rt) {
      const int prow = rt * 16 + lm;
      const float p0 = __builtin_amdgcn_exp2f(S[rt][0]);
      const float p1 = __builtin_amdgcn_exp2f(S[rt][1]);
      const float p2 = __builtin_amdgcn_exp2f(S[rt][2]);
      const float p3 = __builtin_amdgcn_exp2f(S[rt][3]);
      l_run[rt] += (p0 + p1) + (p2 + p3);
      bf16x4_t w4 = {(bf16_t)p0, (bf16_t)p1, (bf16_t)p2, (bf16_t)p3};
      *(bf16x4_t*)&Pl[buf][prow][(w * 16 + 4 * l4) ^ swz] = w4;
    }

    asm volatile("s_waitcnt lgkmcnt(0)" ::: "memory");   // P visible; prev reads drained
    __builtin_amdgcn_s_barrier();

    // ---- PV: 4 barrier-free substeps x 32 keys of the wave's half ----
#pragma unroll
    for (int s4 = 0; s4 < 4; ++s4) {
      bf16x8_t pa[4];
#pragma unroll
      for (int rt = 0; rt < 4; ++rt)
        pa[rt] = *(const bf16x8_t*)&Pl[buf][rt * 16 + lm][(kh * 128 + s4 * 32 + l4 * 8) ^ swz];
      const int knx = (it * KT + (s4 + 2) * 32) & 127;   // next substep offset in half
      const int kbase_nx = ((it + (s4 >= 2)) * KT) & (N_ - 1);
      if ((s4 & 1) == 0) {
#pragma unroll
        for (int ct = 0; ct < 2; ++ct)
#pragma unroll
          for (int rt = 0; rt < 4; ++rt)
            acc[ct][rt] = __builtin_amdgcn_mfma_f32_16x16x32_bf16(vf0[ct], pa[rt], acc[ct][rt], 0, 0, 0);
#pragma unroll
        for (int ct = 0; ct < 2; ++ct)
          vf0[ct] = *(const bf16x8_t*)(vbase + (size_t)(ct * 16) * N_ + kbase_nx + knx);
      } else {
#pragma unroll
        for (int ct = 0; ct < 2; ++ct)
#pragma unroll
          for (int rt = 0; rt < 4; ++rt)
            acc[ct][rt] = __builtin_amdgcn_mfma_f32_16x16x32_bf16(vf1[ct], pa[rt], acc[ct][rt], 0, 0, 0);
#pragma unroll
        for (int ct = 0; ct < 2; ++ct)
          vf1[ct] = *(const bf16x8_t*)(vbase + (size_t)(ct * 16) * N_ + kbase_nx + knx);
      }
    }

    kf = kn;
  }

  // ---- l reduce: lane-local (16 keys/iter summed) -> per-q -> all 16 waves ----
#pragma unroll
  for (int rt = 0; rt < 4; ++rt) {
    l_run[rt] += __shfl_xor(l_run[rt], 16);
    l_run[rt] += __shfl_xor(l_run[rt], 32);
  }
  if (l4 == 0) {
#pragma unroll
    for (int rt = 0; rt < 4; ++rt) Lx[rt * 16 + lm][w] = l_run[rt];
  }

  // ---- acc combine: kh=1 waves export acc via retired Pl space ----
  float* Ax = (float*)&Pl[0][0][0];   // 64KB f32 scratch: [8 cg][64 q][32 ch]
  asm volatile("s_waitcnt lgkmcnt(0)" ::: "memory");
  __builtin_amdgcn_s_barrier();       // Pl PV-reads done; Lx visible

  if (kh == 1) {
#pragma unroll
    for (int rt = 0; rt < 4; ++rt)
#pragma unroll
      for (int ct = 0; ct < 2; ++ct)
        *(f32x4*)&Ax[((cg * 64) + rt * 16 + lm) * 32 + ct * 16 + 4 * l4] = acc[ct][rt];
  }
  asm volatile("s_waitcnt lgkmcnt(0)" ::: "memory");
  __builtin_amdgcn_s_barrier();

  if (kh == 0) {
    const float g = gamma[0];
#pragma unroll
    for (int rt = 0; rt < 4; ++rt) {
      const f32x4 s0 = *(const f32x4*)&Lx[rt * 16 + lm][0];
      const f32x4 s1 = *(const f32x4*)&Lx[rt * 16 + lm][4];
      const f32x4 s2 = *(const f32x4*)&Lx[rt * 16 + lm][8];
      const f32x4 s3 = *(const f32x4*)&Lx[rt * 16 + lm][12];
      const float lt = (((s0[0] + s0[1]) + (s0[2] + s0[3])) + ((s1[0] + s1[1]) + (s1[2] + s1[3]))) +
                       (((s2[0] + s2[1]) + (s2[2] + s2[3])) + ((s3[0] + s3[1]) + (s3[2] + s3[3])));
      const float inv = 1.f / lt;
      const int n = q0 + rt * 16 + lm;
#pragma unroll
      for (int ct = 0; ct < 2; ++ct) {
        const f32x4 other = *(const f32x4*)&Ax[((cg * 64) + rt * 16 + lm) * 32 + ct * 16 + 4 * l4];
#pragma unroll
        for (int r = 0; r < 4; ++r) {
          const int c = cg * 32 + ct * 16 + 4 * l4 + r;
          const size_t idx = ((size_t)(b * C_ + c)) * N_ + n;
          out[idx] = g * ((acc[ct][rt][r] + other[r]) * inv) + x[idx];
        }
      }
    }
  }
}

extern "C" void kernel_launch(void* const* d_in, const int* in_sizes, int n_in,
                              void* d_out, int out_size, void* d_ws, size_t ws_size,
                              hipStream_t stream) {
  const float* x     = (const float*)d_in[0];
  const float* wq    = (const float*)d_in[1];
  const float* bq    = (const float*)d_in[2];
  const float* wk    = (const float*)d_in[3];
  const float* bk    = (const float*)d_in[4];
  const float* wv    = (const float*)d_in[5];
  const float* bv    = (const float*)d_in[6];
  const float* gamma = (const float*)d_in[7];
  float* out = (float*)d_out;

  bf16_t* Qh = (bf16_t*)d_ws;
  bf16_t* Kh = Qh + (size_t)B_ * N_ * D_;
  bf16_t* Vh = Kh + (size_t)B_ * N_ * D_;
  bf16_t* Wb = Vh + (size_t)B_ * C_ * N_;

  cast_w_kernel<<<320, 256, 0, stream>>>(wq, wk, wv, Wb);
  proj_kernel<<<256, 256, 0, stream>>>(x, Wb, bq, bk, bv, Qh, Kh, Vh);
  attn_kernel<<<256, 1024, 0, stream>>>(Qh, Kh, Vh, x, gamma, out);
}

// Round 15
// 92.948 us; speedup vs baseline: 1.6280x; 1.0367x over previous
//
#include <hip/hip_runtime.h>
#include <hip/hip_bf16.h>
#include <stdint.h>

#define B_ 4
#define C_ 256
#define N_ 4096
#define D_ 32
#define KT 256   // keys per outer iteration

typedef __bf16 bf16_t;
typedef __bf16 bf16x4_t __attribute__((ext_vector_type(4)));
typedef __bf16 bf16x8_t __attribute__((ext_vector_type(8)));
typedef float  f32x4    __attribute__((ext_vector_type(4)));

// ---------------------------------------------------------------------------
// cast W (wq|wk|wv) -> Wb bf16 [320][256]
// ---------------------------------------------------------------------------
__global__ __launch_bounds__(256) void cast_w_kernel(
    const float* __restrict__ wq, const float* __restrict__ wk,
    const float* __restrict__ wv, bf16_t* __restrict__ Wb)
{
  const int gr = blockIdx.x;
  const int t  = threadIdx.x;
  float v;
  if (gr < 32)      v = wq[gr * C_ + t];
  else if (gr < 64) v = wk[(gr - 32) * C_ + t];
  else              v = wv[(gr - 64) * C_ + t];
  Wb[gr * C_ + t] = (bf16_t)v;
}

// ---------------------------------------------------------------------------
// Projection GEMM with fused transpose (R12, unchanged).
// ---------------------------------------------------------------------------
__global__ __launch_bounds__(256) void proj_kernel(
    const float* __restrict__ x, const bf16_t* __restrict__ Wb,
    const float* __restrict__ bq, const float* __restrict__ bk,
    const float* __restrict__ bv,
    bf16_t* __restrict__ Qh, bf16_t* __restrict__ Kh, bf16_t* __restrict__ Vh)
{
  __shared__ float xs[64][65];
  const int bi = blockIdx.x;
  const int b  = bi & 3;
  const int n0 = (bi >> 2) * 64;
  const int t = threadIdx.x, w = t >> 6, lane = t & 63;
  const int l4 = lane >> 4, lm = lane & 15;

  const f32x4 z4 = {0.f, 0.f, 0.f, 0.f};
  f32x4 acc[5][4];
#pragma unroll
  for (int rt = 0; rt < 5; ++rt)
#pragma unroll
    for (int ct = 0; ct < 4; ++ct) acc[rt][ct] = z4;

  const int lr = t >> 2;
  const int lc = (t & 3) * 16;

#pragma unroll 1
  for (int k0 = 0; k0 < C_; k0 += 64) {
    __syncthreads();
#pragma unroll
    for (int i = 0; i < 4; ++i) {
      const f32x4 v = *(const f32x4*)(x + ((size_t)(b * C_ + k0 + lr)) * N_ + n0 + lc + i * 4);
      xs[lr][lc + i * 4 + 0] = v[0];
      xs[lr][lc + i * 4 + 1] = v[1];
      xs[lr][lc + i * 4 + 2] = v[2];
      xs[lr][lc + i * 4 + 3] = v[3];
    }
    __syncthreads();

    bf16x8_t af[5][2], bfr[4][2];
#pragma unroll
    for (int rt = 0; rt < 5; ++rt)
#pragma unroll
      for (int kc = 0; kc < 2; ++kc)
        af[rt][kc] = *(const bf16x8_t*)(Wb + (size_t)(w * 80 + rt * 16 + lm) * C_ + k0 + kc * 32 + l4 * 8);
#pragma unroll
    for (int ct = 0; ct < 4; ++ct)
#pragma unroll
      for (int kc = 0; kc < 2; ++kc) {
        bf16_t tmp[8];
#pragma unroll
        for (int j = 0; j < 8; ++j)
          tmp[j] = (bf16_t)xs[kc * 32 + l4 * 8 + j][ct * 16 + lm];
        bfr[ct][kc] = *(bf16x8_t*)tmp;
      }
#pragma unroll
    for (int rt = 0; rt < 5; ++rt)
#pragma unroll
      for (int ct = 0; ct < 4; ++ct)
#pragma unroll
        for (int kc = 0; kc < 2; ++kc)
          acc[rt][ct] = __builtin_amdgcn_mfma_f32_16x16x32_bf16(af[rt][kc], bfr[ct][kc], acc[rt][ct], 0, 0, 0);
  }

#pragma unroll
  for (int rt = 0; rt < 5; ++rt)
#pragma unroll
    for (int r = 0; r < 4; ++r) {
      const int gr = w * 80 + rt * 16 + 4 * l4 + r;
      const float bias = (gr < 32) ? bq[gr] : (gr < 64) ? bk[gr - 32] : bv[gr - 64];
#pragma unroll
      for (int ct = 0; ct < 4; ++ct) {
        const int n = n0 + ct * 16 + lm;
        float v = acc[rt][ct][r] + bias;
        if (gr < 32) {
          v *= 1.44269504088896f;
          Qh[((size_t)(b * N_ + n)) * D_ + gr] = (bf16_t)v;
        } else if (gr < 64) {
          Kh[((size_t)(b * N_ + n)) * D_ + (gr - 32)] = (bf16_t)v;
        } else {
          Vh[((size_t)(b * C_ + (gr - 64))) * N_ + n] = (bf16_t)v;
        }
      }
    }
}

// ---------------------------------------------------------------------------
// Flash attention = R8 skeleton + CROSS-ITERATION OVERLAP: between barriers
// each wave runs two independent streams — PV(it) {ds_read pa -> MFMA} and
// S(it+1) {MFMA -> exp2 -> pack -> ds_write to the OTHER P buffer} — hand-
// interleaved into the 4 PV substeps (s4=0 carries S-MFMAs, s4=1/2 carry
// exp2+P-writes, s4=3 carries K(it+2) prefetch). Breaks the block-wide
// S->exp2->PV phase lockstep that pinned all pipes at ~20%.
// Partition/layout/softmax identical to R8: 8 ch-waves x 32ch, keys 8-way,
// fixed-reference exp2, XOR-swizzled double-buffered P, ONE barrier/iter.
// ---------------------------------------------------------------------------
__global__ __launch_bounds__(512, 2) void attn_kernel(
    const bf16_t* __restrict__ Qh, const bf16_t* __restrict__ Kh,
    const bf16_t* __restrict__ Vh, const float* __restrict__ x,
    const float* __restrict__ gamma, float* __restrict__ out)
{
  __shared__ __align__(16) bf16_t Pl[2][64][KT];  // 64 KB double-buffered P
  __shared__ __align__(16) float  Lx[64][12];     // epilogue l exchange

  const int bi = blockIdx.x;
  const int xcd = bi & 7, slot = bi >> 3;
  const int b  = xcd >> 1;                 // 2 XCDs per batch -> K,V,Q L2-resident
  const int q0 = ((xcd & 1) * 32 + slot) * 64;

  const int t = threadIdx.x, w = t >> 6, lane = t & 63;
  const int l4 = lane >> 4, lm = lane & 15;
  const int swz = (lm & 7) << 3;

  const f32x4 z4 = {0.f, 0.f, 0.f, 0.f};

  bf16x8_t qf[4];
#pragma unroll
  for (int rt = 0; rt < 4; ++rt)
    qf[rt] = *(const bf16x8_t*)(Qh + ((size_t)(b * N_ + q0 + rt * 16 + lm)) * D_ + l4 * 8);

  const bf16_t* kbase = Kh + ((size_t)(b * N_ + w * 32 + lm)) * D_ + l4 * 8;
  const bf16_t* vbase = Vh + ((size_t)(b * C_ + w * 32 + lm)) * N_ + l4 * 8;

  f32x4 acc[2][4];
#pragma unroll
  for (int ct = 0; ct < 2; ++ct)
#pragma unroll
    for (int rt = 0; rt < 4; ++rt) acc[ct][rt] = z4;
  float l_run[4] = {0.f, 0.f, 0.f, 0.f};

  // ---- prologue: issue globals early, then P(0) ----
  bf16x8_t kf[2], kn[2];
#pragma unroll
  for (int mt = 0; mt < 2; ++mt)
    kf[mt] = *(const bf16x8_t*)(kbase + (size_t)(mt * 16) * D_);
#pragma unroll
  for (int mt = 0; mt < 2; ++mt)
    kn[mt] = *(const bf16x8_t*)(kbase + (size_t)(KT + mt * 16) * D_);
  bf16x8_t vf0[2][2], vf1[2][2];
#pragma unroll
  for (int ct = 0; ct < 2; ++ct)
#pragma unroll
    for (int kc = 0; kc < 2; ++kc) {
      vf0[ct][kc] = *(const bf16x8_t*)(vbase + (size_t)(ct * 16) * N_ + kc * 32);
      vf1[ct][kc] = *(const bf16x8_t*)(vbase + (size_t)(ct * 16) * N_ + 64 + kc * 32);
    }

  f32x4 S[4][2];
#pragma unroll
  for (int rt = 0; rt < 4; ++rt)
#pragma unroll
    for (int mt = 0; mt < 2; ++mt)
      S[rt][mt] = __builtin_amdgcn_mfma_f32_16x16x32_bf16(kf[mt], qf[rt], z4, 0, 0, 0);
#pragma unroll
  for (int rt = 0; rt < 4; ++rt) {
    const int prow = rt * 16 + lm;
#pragma unroll
    for (int mt = 0; mt < 2; ++mt) {
      const float p0 = __builtin_amdgcn_exp2f(S[rt][mt][0]);
      const float p1 = __builtin_amdgcn_exp2f(S[rt][mt][1]);
      const float p2 = __builtin_amdgcn_exp2f(S[rt][mt][2]);
      const float p3 = __builtin_amdgcn_exp2f(S[rt][mt][3]);
      l_run[rt] += (p0 + p1) + (p2 + p3);
      bf16x4_t w4 = {(bf16_t)p0, (bf16_t)p1, (bf16_t)p2, (bf16_t)p3};
      *(bf16x4_t*)&Pl[0][prow][(w * 32 + mt * 16 + 4 * l4) ^ swz] = w4;
    }
  }
  asm volatile("s_waitcnt lgkmcnt(0)" ::: "memory");
  __builtin_amdgcn_s_barrier();

  // ---- main loop: 15 full iters (PV(it) ∥ S/exp2/P-write(it+1)) ----
#pragma unroll 1
  for (int it = 0; it < N_ / KT - 1; ++it) {
    const int buf = it & 1;
    bf16x8_t pa[4][2];

    // ===== s4 = 0 : pa + S(it+1) MFMAs + PV + vf0 reload =====
#pragma unroll
    for (int rt = 0; rt < 4; ++rt)
#pragma unroll
      for (int kc = 0; kc < 2; ++kc)
        pa[rt][kc] = *(const bf16x8_t*)&Pl[buf][rt * 16 + lm][(0 * 64 + kc * 32 + l4 * 8) ^ swz];
#pragma unroll
    for (int rt = 0; rt < 4; ++rt)
#pragma unroll
      for (int mt = 0; mt < 2; ++mt)
        S[rt][mt] = __builtin_amdgcn_mfma_f32_16x16x32_bf16(kn[mt], qf[rt], z4, 0, 0, 0);
#pragma unroll
    for (int ct = 0; ct < 2; ++ct)
#pragma unroll
      for (int kc = 0; kc < 2; ++kc)
#pragma unroll
        for (int rt = 0; rt < 4; ++rt)
          acc[ct][rt] = __builtin_amdgcn_mfma_f32_16x16x32_bf16(vf0[ct][kc], pa[rt][kc], acc[ct][rt], 0, 0, 0);
    {
      const int knx = (it * KT + 2 * 64) & (N_ - 1);
#pragma unroll
      for (int ct = 0; ct < 2; ++ct)
#pragma unroll
        for (int kc = 0; kc < 2; ++kc)
          vf0[ct][kc] = *(const bf16x8_t*)(vbase + (size_t)(ct * 16) * N_ + knx + kc * 32);
    }

    // ===== s4 = 1 : pa + exp2(rt 0..1) + P-write + PV + vf1 reload =====
#pragma unroll
    for (int rt = 0; rt < 4; ++rt)
#pragma unroll
      for (int kc = 0; kc < 2; ++kc)
        pa[rt][kc] = *(const bf16x8_t*)&Pl[buf][rt * 16 + lm][(1 * 64 + kc * 32 + l4 * 8) ^ swz];
#pragma unroll
    for (int rt = 0; rt < 2; ++rt) {
      const int prow = rt * 16 + lm;
#pragma unroll
      for (int mt = 0; mt < 2; ++mt) {
        const float p0 = __builtin_amdgcn_exp2f(S[rt][mt][0]);
        const float p1 = __builtin_amdgcn_exp2f(S[rt][mt][1]);
        const float p2 = __builtin_amdgcn_exp2f(S[rt][mt][2]);
        const float p3 = __builtin_amdgcn_exp2f(S[rt][mt][3]);
        l_run[rt] += (p0 + p1) + (p2 + p3);
        bf16x4_t w4 = {(bf16_t)p0, (bf16_t)p1, (bf16_t)p2, (bf16_t)p3};
        *(bf16x4_t*)&Pl[buf ^ 1][prow][(w * 32 + mt * 16 + 4 * l4) ^ swz] = w4;
      }
    }
#pragma unroll
    for (int ct = 0; ct < 2; ++ct)
#pragma unroll
      for (int kc = 0; kc < 2; ++kc)
#pragma unroll
        for (int rt = 0; rt < 4; ++rt)
          acc[ct][rt] = __builtin_amdgcn_mfma_f32_16x16x32_bf16(vf1[ct][kc], pa[rt][kc], acc[ct][rt], 0, 0, 0);
    {
      const int knx = (it * KT + 3 * 64) & (N_ - 1);
#pragma unroll
      for (int ct = 0; ct < 2; ++ct)
#pragma unroll
        for (int kc = 0; kc < 2; ++kc)
          vf1[ct][kc] = *(const bf16x8_t*)(vbase + (size_t)(ct * 16) * N_ + knx + kc * 32);
    }

    // ===== s4 = 2 : pa + exp2(rt 2..3) + P-write + PV + vf0 reload =====
#pragma unroll
    for (int rt = 0; rt < 4; ++rt)
#pragma unroll
      for (int kc = 0; kc < 2; ++kc)
        pa[rt][kc] = *(const bf16x8_t*)&Pl[buf][rt * 16 + lm][(2 * 64 + kc * 32 + l4 * 8) ^ swz];
#pragma unroll
    for (int rt = 2; rt < 4; ++rt) {
      const int prow = rt * 16 + lm;
#pragma unroll
      for (int mt = 0; mt < 2; ++mt) {
        const float p0 = __builtin_amdgcn_exp2f(S[rt][mt][0]);
        const float p1 = __builtin_amdgcn_exp2f(S[rt][mt][1]);
        const float p2 = __builtin_amdgcn_exp2f(S[rt][mt][2]);
        const float p3 = __builtin_amdgcn_exp2f(S[rt][mt][3]);
        l_run[rt] += (p0 + p1) + (p2 + p3);
        bf16x4_t w4 = {(bf16_t)p0, (bf16_t)p1, (bf16_t)p2, (bf16_t)p3};
        *(bf16x4_t*)&Pl[buf ^ 1][prow][(w * 32 + mt * 16 + 4 * l4) ^ swz] = w4;
      }
    }
#pragma unroll
    for (int ct = 0; ct < 2; ++ct)
#pragma unroll
      for (int kc = 0; kc < 2; ++kc)
#pragma unroll
        for (int rt = 0; rt < 4; ++rt)
          acc[ct][rt] = __builtin_amdgcn_mfma_f32_16x16x32_bf16(vf0[ct][kc], pa[rt][kc], acc[ct][rt], 0, 0, 0);
    {
      const int knx = (it * KT + 4 * 64) & (N_ - 1);
#pragma unroll
      for (int ct = 0; ct < 2; ++ct)
#pragma unroll
        for (int kc = 0; kc < 2; ++kc)
          vf0[ct][kc] = *(const bf16x8_t*)(vbase + (size_t)(ct * 16) * N_ + knx + kc * 32);
    }

    // ===== s4 = 3 : pa + K(it+2) prefetch + PV + vf1 reload =====
#pragma unroll
    for (int rt = 0; rt < 4; ++rt)
#pragma unroll
      for (int kc = 0; kc < 2; ++kc)
        pa[rt][kc] = *(const bf16x8_t*)&Pl[buf][rt * 16 + lm][(3 * 64 + kc * 32 + l4 * 8) ^ swz];
    {
      const int k0n = ((it + 2) * KT) & (N_ - 1);
#pragma unroll
      for (int mt = 0; mt < 2; ++mt)
        kn[mt] = *(const bf16x8_t*)(kbase + (size_t)(k0n + mt * 16) * D_);
    }
#pragma unroll
    for (int ct = 0; ct < 2; ++ct)
#pragma unroll
      for (int kc = 0; kc < 2; ++kc)
#pragma unroll
        for (int rt = 0; rt < 4; ++rt)
          acc[ct][rt] = __builtin_amdgcn_mfma_f32_16x16x32_bf16(vf1[ct][kc], pa[rt][kc], acc[ct][rt], 0, 0, 0);
    {
      const int knx = (it * KT + 5 * 64) & (N_ - 1);
#pragma unroll
      for (int ct = 0; ct < 2; ++ct)
#pragma unroll
        for (int kc = 0; kc < 2; ++kc)
          vf1[ct][kc] = *(const bf16x8_t*)(vbase + (size_t)(ct * 16) * N_ + knx + kc * 32);
    }

    asm volatile("s_waitcnt lgkmcnt(0)" ::: "memory");   // P(it+1) visible; buf reads drained
    __builtin_amdgcn_s_barrier();
  }

  // ---- tail: PV(15) only ----
  {
    const int buf = (N_ / KT - 1) & 1;
#pragma unroll
    for (int s4 = 0; s4 < 4; ++s4) {
      bf16x8_t pa[4][2];
#pragma unroll
      for (int rt = 0; rt < 4; ++rt)
#pragma unroll
        for (int kc = 0; kc < 2; ++kc)
          pa[rt][kc] = *(const bf16x8_t*)&Pl[buf][rt * 16 + lm][(s4 * 64 + kc * 32 + l4 * 8) ^ swz];
      if ((s4 & 1) == 0) {
#pragma unroll
        for (int ct = 0; ct < 2; ++ct)
#pragma unroll
          for (int kc = 0; kc < 2; ++kc)
#pragma unroll
            for (int rt = 0; rt < 4; ++rt)
              acc[ct][rt] = __builtin_amdgcn_mfma_f32_16x16x32_bf16(vf0[ct][kc], pa[rt][kc], acc[ct][rt], 0, 0, 0);
      } else {
#pragma unroll
        for (int ct = 0; ct < 2; ++ct)
#pragma unroll
          for (int kc = 0; kc < 2; ++kc)
#pragma unroll
            for (int rt = 0; rt < 4; ++rt)
              acc[ct][rt] = __builtin_amdgcn_mfma_f32_16x16x32_bf16(vf1[ct][kc], pa[rt][kc], acc[ct][rt], 0, 0, 0);
      }
      if (s4 < 2) {   // reload for substeps 2/3 of the tail
        const int knx = ((N_ / KT - 1) * KT + (s4 + 2) * 64) & (N_ - 1);
        if ((s4 & 1) == 0) {
#pragma unroll
          for (int ct = 0; ct < 2; ++ct)
#pragma unroll
            for (int kc = 0; kc < 2; ++kc)
              vf0[ct][kc] = *(const bf16x8_t*)(vbase + (size_t)(ct * 16) * N_ + knx + kc * 32);
        } else {
#pragma unroll
          for (int ct = 0; ct < 2; ++ct)
#pragma unroll
            for (int kc = 0; kc < 2; ++kc)
              vf1[ct][kc] = *(const bf16x8_t*)(vbase + (size_t)(ct * 16) * N_ + knx + kc * 32);
        }
      }
    }
  }

  // ---- epilogue: reduce l, then store ----
#pragma unroll
  for (int rt = 0; rt < 4; ++rt) {
    l_run[rt] += __shfl_xor(l_run[rt], 16);
    l_run[rt] += __shfl_xor(l_run[rt], 32);
  }
  if (l4 == 0) {
#pragma unroll
    for (int rt = 0; rt < 4; ++rt) Lx[rt * 16 + lm][w] = l_run[rt];
  }
  asm volatile("s_waitcnt lgkmcnt(0)" ::: "memory");
  __builtin_amdgcn_s_barrier();

  const float g = gamma[0];
#pragma unroll
  for (int rt = 0; rt < 4; ++rt) {
    const f32x4 s0 = *(const f32x4*)&Lx[rt * 16 + lm][0];
    const f32x4 s1 = *(const f32x4*)&Lx[rt * 16 + lm][4];
    const float lt = ((s0[0] + s0[1]) + (s0[2] + s0[3])) + ((s1[0] + s1[1]) + (s1[2] + s1[3]));
    const float inv = 1.f / lt;
    const int n = q0 + rt * 16 + lm;
#pragma unroll
    for (int ct = 0; ct < 2; ++ct) {
#pragma unroll
      for (int r = 0; r < 4; ++r) {
        const int c = w * 32 + ct * 16 + 4 * l4 + r;
        const size_t idx = ((size_t)(b * C_ + c)) * N_ + n;
        out[idx] = g * (acc[ct][rt][r] * inv) + x[idx];
      }
    }
  }
}

extern "C" void kernel_launch(void* const* d_in, const int* in_sizes, int n_in,
                              void* d_out, int out_size, void* d_ws, size_t ws_size,
                              hipStream_t stream) {
  const float* x     = (const float*)d_in[0];
  const float* wq    = (const float*)d_in[1];
  const float* bq    = (const float*)d_in[2];
  const float* wk    = (const float*)d_in[3];
  const float* bk    = (const float*)d_in[4];
  const float* wv    = (const float*)d_in[5];
  const float* bv    = (const float*)d_in[6];
  const float* gamma = (const float*)d_in[7];
  float* out = (float*)d_out;

  bf16_t* Qh = (bf16_t*)d_ws;
  bf16_t* Kh = Qh + (size_t)B_ * N_ * D_;
  bf16_t* Vh = Kh + (size_t)B_ * N_ * D_;
  bf16_t* Wb = Vh + (size_t)B_ * C_ * N_;

  cast_w_kernel<<<320, 256, 0, stream>>>(wq, wk, wv, Wb);
  proj_kernel<<<256, 256, 0, stream>>>(x, Wb, bq, bk, bv, Qh, Kh, Vh);
  attn_kernel<<<256, 512, 0, stream>>>(Qh, Kh, Vh, x, gamma, out);
}